// Round 1
// baseline (146.228 us; speedup 1.0000x reference)
//
#include <hip/hip_runtime.h>

// One 64-lane wave per ray. Lane i owns sample i (and interval i for i<63).
// All intra-ray dependencies (neighbor shifts, cumprod, cumsum, searchsorted)
// are done with wave shuffles (ds_bpermute) -- no LDS, no barriers.

__global__ __launch_bounds__(256) void neus_upsample_kernel(
    const float* __restrict__ rays_o,
    const float* __restrict__ rays_d,
    const float* __restrict__ z_vals,
    const float* __restrict__ sdf,
    const int*   __restrict__ inv_s_ptr,
    float*       __restrict__ out,
    int n_rays)
{
    const int lane = threadIdx.x & 63;
    const int wave = threadIdx.x >> 6;
    const int ray  = blockIdx.x * 4 + wave;
    if (ray >= n_rays) return;

    const float inv_s = (float)inv_s_ptr[0];

    // Coalesced per-lane loads
    const float z = z_vals[ray * 64 + lane];
    const float s = sdf[ray * 64 + lane];

    // Broadcast ray origin/dir (same address across the wave -> cached)
    const float ox = rays_o[ray * 3 + 0];
    const float oy = rays_o[ray * 3 + 1];
    const float oz = rays_o[ray * 3 + 2];
    const float dx = rays_d[ray * 3 + 0];
    const float dy = rays_d[ray * 3 + 1];
    const float dz = rays_d[ray * 3 + 2];

    // inside_sphere per sample
    const float px = ox + dx * z, py = oy + dy * z, pz = oz + dz * z;
    const float radius = sqrtf(px * px + py * py + pz * pz);
    const int inside = (radius < 1.0f) ? 1 : 0;

    // Neighbor (sample i+1) values; lane 63's interval quantities are unused/masked
    const float z_next = __shfl_down(z, 1);
    const float s_next = __shfl_down(s, 1);
    const int   inside_next = __shfl_down(inside, 1);

    // cos_val with running-min against previous interval, clip, sphere mask
    const float cos_raw  = (s_next - s) / (z_next - z + 1e-5f);
    float cos_prev = __shfl_up(cos_raw, 1);
    if (lane == 0) cos_prev = 0.0f;
    float cosv = fminf(cos_prev, cos_raw);
    cosv = fminf(fmaxf(cosv, -1000.0f), 0.0f);
    cosv *= ((inside | inside_next) != 0) ? 1.0f : 0.0f;

    const float mid  = 0.5f * (s + s_next);
    const float dist = z_next - z;
    const float pe = mid - cosv * dist * 0.5f;
    const float ne = mid + cosv * dist * 0.5f;
    const float pc = 1.0f / (1.0f + expf(-pe * inv_s));
    const float nc = 1.0f / (1.0f + expf(-ne * inv_s));
    const float alpha = (pc - nc + 1e-5f) / (pc + 1e-5f);   // in (0, 1]

    // trans = exclusive cumprod of (1 - alpha + 1e-7) over intervals 0..62
    float p = (lane < 63) ? (1.0f - alpha + 1e-7f) : 1.0f;
    #pragma unroll
    for (int off = 1; off < 64; off <<= 1) {
        float v = __shfl_up(p, off);
        if (lane >= off) p *= v;
    }
    float trans = __shfl_up(p, 1);
    if (lane == 0) trans = 1.0f;

    // weights (+1e-5 from sample_pdf_det); lane 63 contributes 0
    const float w = (lane < 63) ? (alpha * trans + 1e-5f) : 0.0f;

    // Inclusive cumsum of w; total = inclusive sum at lane 63.
    float q = w;
    #pragma unroll
    for (int off = 1; off < 64; off <<= 1) {
        float v = __shfl_up(q, off);
        if (lane >= off) q += v;
    }
    const float total = __shfl(q, 63);           // sum of all weights
    // cdf entry at index `lane`: 0 at lane 0, else normalized exclusive sum.
    float C = __shfl_up(q, 1);
    C = (lane == 0) ? 0.0f : (C / total);        // C[63] == 1 (up to rounding)

    // u = linspace(0.5/64, 1 - 0.5/64, 64)
    const float u = ((float)lane + 0.5f) * (1.0f / 64.0f);

    // searchsorted(C, u, side='right') over 64 entries: 7 guarded bisection steps
    int lo = 0, hi = 64;
    #pragma unroll
    for (int it = 0; it < 7; ++it) {
        const int m = (lo + hi) >> 1;
        const float cm = __shfl(C, m & 63);      // shfl executed by all lanes
        if (lo < hi) {
            if (cm <= u) lo = m + 1; else hi = m;
        }
    }
    int below = lo - 1; if (below < 0) below = 0;
    int above = (lo < 63) ? lo : 63;

    const float cb = __shfl(C, below);
    const float ca = __shfl(C, above);
    const float bb = __shfl(z, below);
    const float ba = __shfl(z, above);

    float denom = ca - cb;
    if (denom < 1e-5f) denom = 1.0f;
    const float t = (u - cb) / denom;

    out[ray * 64 + lane] = bb + t * (ba - bb);
}

extern "C" void kernel_launch(void* const* d_in, const int* in_sizes, int n_in,
                              void* d_out, int out_size, void* d_ws, size_t ws_size,
                              hipStream_t stream) {
    const float* rays_o = (const float*)d_in[0];
    const float* rays_d = (const float*)d_in[1];
    const float* z_vals = (const float*)d_in[2];
    const float* sdf    = (const float*)d_in[3];
    // d_in[4] = n_importance (== 64, matches wave width; hardcoded in kernel)
    const int*   inv_s  = (const int*)d_in[5];
    float* out = (float*)d_out;

    const int n_rays = in_sizes[0] / 3;          // 131072
    const int blocks = (n_rays + 3) / 4;         // 4 rays (waves) per 256-thr block

    neus_upsample_kernel<<<blocks, 256, 0, stream>>>(
        rays_o, rays_d, z_vals, sdf, inv_s, out, n_rays);
}

// Round 2
// 128.169 us; speedup vs baseline: 1.1409x; 1.1409x over previous
//
#include <hip/hip_runtime.h>

// One 64-lane wave per ray; lane i owns sample i (interval i for i<63).
// All intra-ray couplings via DPP (scans, shifts) + ds_bpermute (bisection).
// VALU diet: v_rcp_f32 instead of precise fdiv, v_exp_f32 via __expf,
// r^2 compare instead of sqrt, DPP scans instead of guarded shfl scans.

template<int CTRL, int RM>
__device__ __forceinline__ float dpp_mov(float old, float x) {
    return __int_as_float(__builtin_amdgcn_update_dpp(
        __float_as_int(old), __float_as_int(x), CTRL, RM, 0xF, false));
}
// DPP ctrl encodings (gfx9/CDNA): row_shr:N = 0x110|N, wave_shl:1 = 0x130,
// wave_shr:1 = 0x138, row_bcast:15 = 0x142, row_bcast:31 = 0x143.

__device__ __forceinline__ float fast_rcp(float x) {
    return __builtin_amdgcn_rcpf(x);
}

__global__ __launch_bounds__(256) void neus_upsample_kernel(
    const float* __restrict__ rays_o,
    const float* __restrict__ rays_d,
    const float* __restrict__ z_vals,
    const float* __restrict__ sdf,
    const int*   __restrict__ inv_s_ptr,
    float*       __restrict__ out,
    int n_rays)
{
    const int lane = threadIdx.x & 63;
    const int ray  = (blockIdx.x << 2) + (threadIdx.x >> 6);
    if (ray >= n_rays) return;

    const float inv_s = (float)inv_s_ptr[0];
    const int   base  = ray * 64 + lane;

    const float z = z_vals[base];
    const float s = sdf[base];

    // Wave-uniform ray params (broadcast loads, L1-resident)
    const float ox = rays_o[ray * 3 + 0];
    const float oy = rays_o[ray * 3 + 1];
    const float oz = rays_o[ray * 3 + 2];
    const float dx = rays_d[ray * 3 + 0];
    const float dy = rays_d[ray * 3 + 1];
    const float dz = rays_d[ray * 3 + 2];
    // |o + d z|^2 = z^2 + 2(o.d) z + |o|^2   (|d| == 1)
    const float a  = ox * ox + oy * oy + oz * oz;
    const float b2 = 2.0f * (ox * dx + oy * dy + oz * dz);

    // Neighbor (lane+1) values; lane 63 keeps self (its interval is masked)
    const float z_next = dpp_mov<0x130, 0xF>(z, z);   // wave_shl:1
    const float s_next = dpp_mov<0x130, 0xF>(s, s);

    // inside_sphere for sample i and i+1 (no sqrt: compare r^2)
    const float r2  = fmaf(z,      z      + b2, a);
    const float r2n = fmaf(z_next, z_next + b2, a);
    const float insideE = ((r2 < 1.0f) || (r2n < 1.0f)) ? 1.0f : 0.0f;

    // cos_val with running min vs previous interval, clip, sphere mask
    const float cos_raw = (s_next - s) * fast_rcp(z_next - z + 1e-5f);
    float cosv = fminf(dpp_mov<0x138, 0xF>(0.0f, cos_raw), cos_raw); // wave_shr:1
    cosv = fminf(fmaxf(cosv, -1000.0f), 0.0f) * insideE;

    const float mid = 0.5f * (s + s_next);
    const float hd  = 0.5f * (z_next - z);
    const float pe  = fmaf(-cosv, hd, mid);
    const float ne  = fmaf( cosv, hd, mid);
    const float pc  = fast_rcp(1.0f + __expf(-pe * inv_s));
    const float nc  = fast_rcp(1.0f + __expf(-ne * inv_s));
    const float alpha = (pc - nc + 1e-5f) * fast_rcp(pc + 1e-5f); // in (0,1]

    // trans = exclusive cumprod of (1 - alpha + 1e-7) over intervals 0..62
    float f = (lane < 63) ? (1.0f - alpha + 1e-7f) : 1.0f;
    f *= dpp_mov<0x111, 0xF>(1.0f, f);   // row_shr:1
    f *= dpp_mov<0x112, 0xF>(1.0f, f);   // row_shr:2
    f *= dpp_mov<0x114, 0xF>(1.0f, f);   // row_shr:4
    f *= dpp_mov<0x118, 0xF>(1.0f, f);   // row_shr:8
    f *= dpp_mov<0x142, 0xA>(1.0f, f);   // row_bcast:15 -> rows 1,3
    f *= dpp_mov<0x143, 0xC>(1.0f, f);   // row_bcast:31 -> rows 2,3
    const float trans = dpp_mov<0x138, 0xF>(1.0f, f);   // exclusive shift

    // weights (+1e-5 from sample_pdf_det); lane 63 contributes 0
    float q = (lane < 63) ? fmaf(alpha, trans, 1e-5f) : 0.0f;
    q += dpp_mov<0x111, 0xF>(0.0f, q);
    q += dpp_mov<0x112, 0xF>(0.0f, q);
    q += dpp_mov<0x114, 0xF>(0.0f, q);
    q += dpp_mov<0x118, 0xF>(0.0f, q);
    q += dpp_mov<0x142, 0xA>(0.0f, q);
    q += dpp_mov<0x143, 0xC>(0.0f, q);

    const float total = __int_as_float(
        __builtin_amdgcn_readlane(__float_as_int(q), 63));
    const float rtot  = fast_rcp(total);
    // Normalized exclusive CDF at index `lane` (C[0]=0, C[63]=~1)
    const float C = dpp_mov<0x138, 0xF>(0.0f, q) * rtot;

    const float u = ((float)lane + 0.5f) * 0.015625f;

    // searchsorted(C, u, 'right') over 64 sorted entries: branchless 6-step
    int pos = 0;
    #pragma unroll
    for (int st = 32; st; st >>= 1) {
        const float c = __shfl(C, pos + st - 1);
        if (c <= u) pos += st;
    }
    // pos in [1,63] (C[0]=0<=u always; C[63]~1>u always) -> below=pos-1, above=pos
    const float cb = __shfl(C, pos - 1);
    const float ca = __shfl(C, pos);
    const float bb = __shfl(z, pos - 1);
    const float ba = __shfl(z, pos);

    float denom = ca - cb;
    denom = (denom < 1e-5f) ? 1.0f : denom;
    const float t = (u - cb) * fast_rcp(denom);

    out[base] = fmaf(t, ba - bb, bb);
}

extern "C" void kernel_launch(void* const* d_in, const int* in_sizes, int n_in,
                              void* d_out, int out_size, void* d_ws, size_t ws_size,
                              hipStream_t stream) {
    const float* rays_o = (const float*)d_in[0];
    const float* rays_d = (const float*)d_in[1];
    const float* z_vals = (const float*)d_in[2];
    const float* sdf    = (const float*)d_in[3];
    // d_in[4] = n_importance (== 64 == wave width, hardcoded)
    const int*   inv_s  = (const int*)d_in[5];
    float* out = (float*)d_out;

    const int n_rays = in_sizes[0] / 3;          // 131072
    const int blocks = (n_rays + 3) / 4;         // 4 waves (rays) per block

    neus_upsample_kernel<<<blocks, 256, 0, stream>>>(
        rays_o, rays_d, z_vals, sdf, inv_s, out, n_rays);
}